// Round 8
// baseline (225.807 us; speedup 1.0000x reference)
//
#include <hip/hip_runtime.h>
#include <hip/hip_bf16.h>

// ContrastiveLoss: N=16384, D=128.
// loss = mean_i log1p(rep_i / (att_i + EPS)), rep_i = mean_j exp(-(sq1_i+sq2_j-2*x_i.y_j))
// att_i = exp(-||x_i - y_i||^2);  TAU=0.5 => 2*TAU = 1.
// exp folded to native exp2: B2 pre-scaled by 2/ln2, sq1/sq2 by 1/ln2; sq1 stored
// NEGATED so the MFMA accumulator is initialized with -(s1'+s2') and the
// epilogue is p += exp2(acc). Underflow guard: exp2f(x) == 0.0f (incl.
// subnormal range) for x < -149; for this data acc ~ -370 +- 45, so the
// transcendental block is skipped essentially always (exact: skipped values
// are exactly 0 in fp32, matching the fp32 reference's own underflow).
// Outputs: [loss, mean(att), mean(rep)]  (3 fp32 scalars)

#define EPS 1e-8f
#define D_DIM 128
#define INV_LN2 1.44269504088896f
#define SCALE_B 2.88539008177793f   // 2/ln2
#define NCHUNK 8                    // column chunks (XCD count)
#define TCOLS 64                    // cols per B-tile
#define NT 32                       // B-tiles per chunk (2048 cols)
#define BM 64                       // rows per block

typedef __attribute__((ext_vector_type(8))) short bf16x8;
typedef __attribute__((ext_vector_type(4))) float f32x4;

typedef __attribute__((address_space(1))) const unsigned int gu32_t;
typedef __attribute__((address_space(3))) unsigned int lu32_t;

static __device__ inline void gload_lds16(const void* g, void* l) {
    // 16-byte-per-lane global -> LDS direct copy (wave-uniform LDS base + lane*16)
    __builtin_amdgcn_global_load_lds((gu32_t*)g, (lu32_t*)l, 16, 0, 0);
}

static __device__ inline ushort f2bf(float x) {
    union { __hip_bfloat16 h; ushort u; } cvt;
    cvt.h = __float2bfloat16(x);
    return cvt.u;
}

// 4 waves/block, one row per wave: row norms (log2 domain; sq1 negated),
// attraction, bf16 casts (B2 pre-scaled by 2/ln2).
__global__ __launch_bounds__(256) void prep_kernel(
    const float* __restrict__ X1, const float* __restrict__ X2,
    ushort* __restrict__ B1, ushort* __restrict__ B2,
    float* __restrict__ sq1n, float* __restrict__ sq2,
    float* __restrict__ att)
{
    const int w = threadIdx.x >> 6;
    const int l = threadIdx.x & 63;           // 2 floats each -> 128
    const int i = blockIdx.x * 4 + w;
    const float2 a = ((const float2*)(X1 + (size_t)i * D_DIM))[l];
    const float2 b = ((const float2*)(X2 + (size_t)i * D_DIM))[l];

    ushort2 pa; pa.x = f2bf(a.x);           pa.y = f2bf(a.y);
    ushort2 pb; pb.x = f2bf(b.x * SCALE_B); pb.y = f2bf(b.y * SCALE_B);
    ((ushort2*)(B1 + (size_t)i * D_DIM))[l] = pa;
    ((ushort2*)(B2 + (size_t)i * D_DIM))[l] = pb;

    float s1 = a.x * a.x + a.y * a.y;
    float s2 = b.x * b.x + b.y * b.y;
    float dx = a.x - b.x, dy = a.y - b.y;
    float ps = dx * dx + dy * dy;
    #pragma unroll
    for (int m = 32; m; m >>= 1) {
        s1 += __shfl_xor(s1, m, 64);
        s2 += __shfl_xor(s2, m, 64);
        ps += __shfl_xor(ps, m, 64);
    }
    if (l == 0) {
        sq1n[i] = -s1 * INV_LN2;   // negated log2-domain row norm
        sq2[i]  =  s2 * INV_LN2;
        att[i]  = __expf(-ps);
    }
}

// Fused cross-GEMM + exp2 + row-sum, BARRIER-FREE main loop.
// Block = 64 rows x 2048 cols; 4 independent waves, each owning a 16-col
// stripe. A-tile staged once to LDS (swizzled) then held in registers
// (aR: 16 frags). B fragments are streamed DIRECTLY from L2 to registers
// (B chunk = 512 KB, L2-resident per XCD; each load = 16 cols x 64 B
// contiguous -> fully sector-efficient), software-pipelined one k-chunk
// ahead; the compiler schedules the vmcnt waits (no barriers, no LDS ring).
// acc init = -(s1'+s2'); epilogue = underflow-guarded p += exp2(acc).
// Row partials in registers; one plain store per (row,stripe); zero atomics.
__global__ __launch_bounds__(256, 4) void cross_kernel(
    const ushort* __restrict__ B1, const ushort* __restrict__ B2,
    const float* __restrict__ sq1n, const float* __restrict__ sq2,
    float* __restrict__ partials, int Ntot)
{
    __shared__ char  ldsA[BM * 256];     // 16 KB A tile (swizzled layout)
    __shared__ float ldsS1[BM];          // negated scaled row norms
    __shared__ float ldsS2[NT * TCOLS];  // scaled col norms, whole chunk (8 KB)

    const int t    = threadIdx.x;
    const int lane = t & 63;
    const int wx   = t >> 6;             // 0..3 col stripe
    const int lr   = lane & 15;
    const int kg   = lane >> 4;          // k-group == C/D row group

    const int brow = blockIdx.y * BM;
    const int ccol = blockIdx.x * (NT * TCOLS);

    const char* gA  = (const char*)(B1 + (size_t)brow * D_DIM);   // 16 KB contig
    const char* gBc = (const char*)(B2 + (size_t)ccol * D_DIM);   // 512 KB chunk

    // ---- stage A (16 KB) via global_load_lds; stage S1/S2 ----
    #pragma unroll
    for (int it = 0; it < 4; ++it) {
        const unsigned Lb  = it * 4096u + wx * 1024u;
        const unsigned L   = Lb + lane * 16u;
        const unsigned src = L ^ (((L >> 8) & 15u) << 4);
        gload_lds16(gA + src, ldsA + Lb);
    }
    if (t < BM) ldsS1[t] = sq1n[brow + t];
    ((float4*)ldsS2)[t]       = ((const float4*)(sq2 + ccol))[t];
    ((float4*)ldsS2)[t + 256] = ((const float4*)(sq2 + ccol))[t + 256];
    __syncthreads();   // only barrier in the kernel

    // ---- A fragments -> registers (held for whole kernel) ----
    bf16x8 aR[16];     // [m][kc] flattened m*4+kc
    #pragma unroll
    for (int m = 0; m < 4; ++m) {
        const int row = m * 16 + lr;
        #pragma unroll
        for (int kc = 0; kc < 4; ++kc) {
            const unsigned addr = (unsigned)(row * 256 + kc * 64 + kg * 16)
                                  ^ ((unsigned)lr << 4);
            aR[m * 4 + kc] = *(const bf16x8*)(ldsA + addr);
        }
    }

    // ---- B stream: per-lane byte offset within the chunk ----
    // col (local) = tt*64 + wx*16 + lr; byte = col*256 + kg*16 + kc*64
    const unsigned voff = (unsigned)((wx * 16 + lr) * 256 + kg * 16);

    // preload tile 0 fragments
    bf16x8 bF[4];
    #pragma unroll
    for (int kc = 0; kc < 4; ++kc)
        bF[kc] = *(const bf16x8*)(gBc + voff + kc * 64);

    float p[4][4];     // row partials across ALL tiles
    #pragma unroll
    for (int m = 0; m < 4; ++m)
        #pragma unroll
        for (int r = 0; r < 4; ++r)
            p[m][r] = 0.f;

    for (int tt = 0; tt < NT; ++tt) {
        const float s2c = ldsS2[tt * TCOLS + wx * 16 + lr];

        // acc init = -(s1' + s2')
        f32x4 acc[4];
        #pragma unroll
        for (int m = 0; m < 4; ++m) {
            const float4 ns1v = *(const float4*)(ldsS1 + m * 16 + kg * 4);
            acc[m] = (f32x4){ns1v.x - s2c, ns1v.y - s2c,
                             ns1v.z - s2c, ns1v.w - s2c};
        }

        // next tile's B base (clamped redundant load on the last iter)
        const int ttn = (tt + 1 < NT) ? (tt + 1) : tt;
        const char* nb = gBc + voff + (unsigned)ttn * (TCOLS * 256u);

        // MFMA: K=128 in 4 chunks; consume bF[kc], refill it for tile tt+1
        #pragma unroll
        for (int kc = 0; kc < 4; ++kc) {
            const bf16x8 bcur = bF[kc];
            bF[kc] = *(const bf16x8*)(nb + kc * 64);
            #pragma unroll
            for (int m = 0; m < 4; ++m)
                acc[m] = __builtin_amdgcn_mfma_f32_16x16x32_bf16(
                    aR[m * 4 + kc], bcur, acc[m], 0, 0, 0);
        }

        // ---- underflow-guarded epilogue ----
        // exp2f(x) == 0.0f exactly for x < -149 (below subnormal range).
        float mxa = fmaxf(fmaxf(acc[0][0], acc[0][1]), fmaxf(acc[0][2], acc[0][3]));
        float mxb = fmaxf(fmaxf(acc[1][0], acc[1][1]), fmaxf(acc[1][2], acc[1][3]));
        float mxc = fmaxf(fmaxf(acc[2][0], acc[2][1]), fmaxf(acc[2][2], acc[2][3]));
        float mxd = fmaxf(fmaxf(acc[3][0], acc[3][1]), fmaxf(acc[3][2], acc[3][3]));
        const float mx = fmaxf(fmaxf(mxa, mxb), fmaxf(mxc, mxd));
        if (__any(mx > -149.0f)) {
            #pragma unroll
            for (int m = 0; m < 4; ++m)
                #pragma unroll
                for (int r = 0; r < 4; ++r)
                    p[m][r] += __builtin_amdgcn_exp2f(acc[m][r]);
        }
    }

    // ---- reduce partials over the 16 col-lanes; one store per (row, wx) ----
    const size_t plane = (size_t)(blockIdx.x * 4 + wx) * (size_t)Ntot;
    #pragma unroll
    for (int m = 0; m < 4; ++m) {
        #pragma unroll
        for (int r = 0; r < 4; ++r) {
            float v = p[m][r];
            v += __shfl_xor(v, 1, 64);
            v += __shfl_xor(v, 2, 64);
            v += __shfl_xor(v, 4, 64);
            v += __shfl_xor(v, 8, 64);
            if (lr == 0)
                partials[plane + brow + m * 16 + kg * 4 + r] = v;
        }
    }
}

// Per-row finish: rep_i = (sum of planes)/N, loss term, att; block-reduce the
// three sums -> blocksums[3][64]. 64 blocks x 256 threads, one i per thread.
__global__ __launch_bounds__(256) void rowsum_kernel(
    const float* __restrict__ partials, const float* __restrict__ att,
    float* __restrict__ blocksums, int N)
{
    __shared__ float sm[3][4];
    const int i = blockIdx.x * 256 + threadIdx.x;
    const float inv = 1.0f / (float)N;
    float s = 0.f;
    #pragma unroll
    for (int pl = 0; pl < 4 * NCHUNK; ++pl)
        s += partials[(size_t)pl * N + i];
    const float rp = s * inv;
    const float at = att[i];
    float ls = log1pf(rp / (at + EPS));
    float sa = at;
    float sr = rp;
    #pragma unroll
    for (int m = 32; m; m >>= 1) {
        ls += __shfl_xor(ls, m, 64);
        sa += __shfl_xor(sa, m, 64);
        sr += __shfl_xor(sr, m, 64);
    }
    const int w = threadIdx.x >> 6, lane = threadIdx.x & 63;
    if (lane == 0) { sm[0][w] = ls; sm[1][w] = sa; sm[2][w] = sr; }
    __syncthreads();
    if (threadIdx.x < 3) {
        const float v = sm[threadIdx.x][0] + sm[threadIdx.x][1]
                      + sm[threadIdx.x][2] + sm[threadIdx.x][3];
        blocksums[threadIdx.x * 64 + blockIdx.x] = v;
    }
}

// Final: 3 waves, wave w reduces blocksums[w][0..63] -> out[w] / N.
__global__ __launch_bounds__(192) void final_kernel(
    const float* __restrict__ blocksums, float* __restrict__ out, int N)
{
    const int w = threadIdx.x >> 6;      // 0..2 output component
    const int lane = threadIdx.x & 63;
    float v = blocksums[w * 64 + lane];
    #pragma unroll
    for (int m = 32; m; m >>= 1) v += __shfl_xor(v, m, 64);
    if (lane == 0) out[w] = v / (float)N;
}

extern "C" void kernel_launch(void* const* d_in, const int* in_sizes, int n_in,
                              void* d_out, int out_size, void* d_ws, size_t ws_size,
                              hipStream_t stream)
{
    const float* X1 = (const float*)d_in[0];
    const float* X2 = (const float*)d_in[1];
    const int N = in_sizes[0] / D_DIM;   // 16384
    float* out = (float*)d_out;

    char* ws = (char*)d_ws;
    ushort* B1 = (ushort*)ws;                                  // N*128*2 B
    ushort* B2 = (ushort*)(ws + (size_t)N * D_DIM * 2);        // N*128*2 B
    float* sq1n = (float*)(ws + (size_t)N * D_DIM * 4);
    float* sq2 = sq1n + N;
    float* att = sq2 + N;
    float* partials = att + N;           // [4*NCHUNK][N] = 2 MB
    float* blocksums = partials + (size_t)4 * NCHUNK * N;   // 192 floats
    // total ws use ~= 10.4 MB

    prep_kernel<<<N / 4, 256, 0, stream>>>(X1, X2, B1, B2, sq1n, sq2, att);
    dim3 grid(NCHUNK, N / BM);
    cross_kernel<<<grid, 256, 0, stream>>>(B1, B2, sq1n, sq2, partials, N);
    rowsum_kernel<<<N / 256, 256, 0, stream>>>(partials, att, blocksums, N);
    final_kernel<<<1, 192, 0, stream>>>(blocksums, out, N);
}

// Round 9
// 82.318 us; speedup vs baseline: 2.7431x; 2.7431x over previous
//
#include <hip/hip_runtime.h>
#include <hip/hip_bf16.h>

// ContrastiveLoss: N=16384, D=128.
// loss = mean_i log1p(rep_i / (att_i + EPS)), rep_i = mean_j exp(-(sq1_i+sq2_j-2*x_i.y_j))
// att_i = exp(-||x_i - y_i||^2);  TAU=0.5 => 2*TAU = 1.
// exp folded to native exp2: B2 pre-scaled by 2/ln2, sq1/sq2 by 1/ln2; sq1 stored
// NEGATED so the MFMA accumulator is initialized with -(s1'+s2') and the
// epilogue is p += exp2(acc). Underflow guard: exp2f(x) == 0.0f (incl.
// subnormal range) for x < -149; for this data acc ~ -370 +- 45, so the
// transcendental block is skipped essentially always (exact: skipped values
// are exactly 0 in fp32, matching the fp32 reference's own underflow).
// Outputs: [loss, mean(att), mean(rep)]  (3 fp32 scalars)

#define EPS 1e-8f
#define D_DIM 128
#define INV_LN2 1.44269504088896f
#define SCALE_B 2.88539008177793f   // 2/ln2
#define NCHUNK 8                    // column chunks (XCD count)
#define TCOLS 64                    // cols per B-tile
#define NT 32                       // B-tiles per chunk (2048 cols)
#define BM 128                      // rows per block

typedef __attribute__((ext_vector_type(8))) short bf16x8;
typedef __attribute__((ext_vector_type(4))) float f32x4;

typedef __attribute__((address_space(1))) const unsigned int gu32_t;
typedef __attribute__((address_space(3))) unsigned int lu32_t;

static __device__ inline void gload_lds16(const void* g, void* l) {
    // 16-byte-per-lane global -> LDS direct copy (wave-uniform LDS base + lane*16)
    __builtin_amdgcn_global_load_lds((gu32_t*)g, (lu32_t*)l, 16, 0, 0);
}

static __device__ inline ushort f2bf(float x) {
    union { __hip_bfloat16 h; ushort u; } cvt;
    cvt.h = __float2bfloat16(x);
    return cvt.u;
}

// 4 waves/block, one row per wave: row norms (log2 domain; sq1 negated),
// attraction, bf16 casts (B2 pre-scaled by 2/ln2).
__global__ __launch_bounds__(256) void prep_kernel(
    const float* __restrict__ X1, const float* __restrict__ X2,
    ushort* __restrict__ B1, ushort* __restrict__ B2,
    float* __restrict__ sq1n, float* __restrict__ sq2,
    float* __restrict__ att)
{
    const int w = threadIdx.x >> 6;
    const int l = threadIdx.x & 63;           // 2 floats each -> 128
    const int i = blockIdx.x * 4 + w;
    const float2 a = ((const float2*)(X1 + (size_t)i * D_DIM))[l];
    const float2 b = ((const float2*)(X2 + (size_t)i * D_DIM))[l];

    ushort2 pa; pa.x = f2bf(a.x);           pa.y = f2bf(a.y);
    ushort2 pb; pb.x = f2bf(b.x * SCALE_B); pb.y = f2bf(b.y * SCALE_B);
    ((ushort2*)(B1 + (size_t)i * D_DIM))[l] = pa;
    ((ushort2*)(B2 + (size_t)i * D_DIM))[l] = pb;

    float s1 = a.x * a.x + a.y * a.y;
    float s2 = b.x * b.x + b.y * b.y;
    float dx = a.x - b.x, dy = a.y - b.y;
    float ps = dx * dx + dy * dy;
    #pragma unroll
    for (int m = 32; m; m >>= 1) {
        s1 += __shfl_xor(s1, m, 64);
        s2 += __shfl_xor(s2, m, 64);
        ps += __shfl_xor(ps, m, 64);
    }
    if (l == 0) {
        sq1n[i] = -s1 * INV_LN2;   // negated log2-domain row norm
        sq2[i]  =  s2 * INV_LN2;
        att[i]  = __expf(-ps);
    }
}

// Fused cross-GEMM + exp2 + row-sum, fine-interleaved schedule (m201-style).
// Block = 128 rows x 2048 cols (32 tiles of 64 cols), 512 threads = 8 waves
// (2 row-halves x 4 col-stripes). A-tile in registers per wave. B-tiles flow
// through a slot-parity double buffer (2 x 16 KB); per tile:
//   ds_read B frags -> lgkmcnt(0)+sched_barrier -> s_barrier
//   -> issue gload(tile+2 -> same slot) -> setprio(1) 16 MFMA setprio(0)
//   -> guarded exp2 epilogue -> s_waitcnt vmcnt(2) -> s_barrier
// Loads span 2 iterations; vmcnt never drained to 0 mid-loop (T3+T4).
// acc init = -(s1'+s2'); row partials in registers; one plain store per
// (row,stripe) -> partials; zero atomics. LDS XOR swizzle byte ^= (row&15)<<4
// on ds_read; gload sources inverse-swizzled (linear dest + inv-swz source).
__global__ __launch_bounds__(512, 4) void cross_kernel(
    const ushort* __restrict__ B1, const ushort* __restrict__ B2,
    const float* __restrict__ sq1n, const float* __restrict__ sq2,
    float* __restrict__ partials, int Ntot)
{
    __shared__ char  bufs[2][16384];     // B slot-parity dbuf; stages A first
    __shared__ float ldsS1[BM];          // negated scaled row norms (0.5 KB)
    __shared__ float ldsS2[NT * TCOLS];  // scaled col norms, whole chunk (8 KB)

    const int t    = threadIdx.x;
    const int lane = t & 63;
    const int wid  = t >> 6;             // 0..7
    const int wy   = wid >> 2;           // 0..1 row half
    const int wx   = wid & 3;            // 0..3 col stripe
    const int lr   = lane & 15;
    const int kg   = lane >> 4;          // k-group == C/D row group

    const int brow = blockIdx.y * BM;
    const int ccol = blockIdx.x * (NT * TCOLS);

    const char* gA = (const char*)(B1 + (size_t)brow * D_DIM);   // 32 KB contig
    const char* gB = (const char*)(B2 + (size_t)ccol * D_DIM);

    // ---- prologue: stage A (32 KB) across both slots; S1/S2 tables ----
    #pragma unroll
    for (int it = 0; it < 4; ++it) {
        const unsigned Lg   = it * 8192u + wid * 1024u;   // 0..31744
        const unsigned half = Lg >> 14;                   // 0 or 1
        const unsigned Lloc = Lg & 16383u;
        const unsigned L    = Lloc + lane * 16u;
        const unsigned src  = L ^ (((L >> 8) & 15u) << 4);
        gload_lds16(gA + (half << 14) + src, bufs[half] + Lloc);
    }
    if (t < BM) ldsS1[t] = sq1n[brow + t];
    ((float4*)ldsS2)[t] = ((const float4*)(sq2 + ccol))[t];   // 512*16B = 8 KB
    __syncthreads();

    // ---- A fragments -> registers (held for whole kernel) ----
    bf16x8 aR[16];     // [m][kc] flattened m*4+kc; this wave's 64-row half
    #pragma unroll
    for (int m = 0; m < 4; ++m) {
        const int row = m * 16 + lr;
        #pragma unroll
        for (int kc = 0; kc < 4; ++kc) {
            const unsigned addr = (unsigned)(row * 256 + kc * 64 + kg * 16)
                                  ^ ((unsigned)lr << 4);
            aR[m * 4 + kc] = *(const bf16x8*)(bufs[wy] + addr);
        }
    }
    __syncthreads();   // all waves done with A: slots free for B

    // ---- issue tile0 -> bufs[0], tile1 -> bufs[1] (2 loads/wave each) ----
    #pragma unroll
    for (int tile = 0; tile < 2; ++tile) {
        const char* gBt = gB + (size_t)tile * (TCOLS * 256u);
        #pragma unroll
        for (int it = 0; it < 2; ++it) {
            const unsigned Lb  = it * 8192u + wid * 1024u;
            const unsigned L   = Lb + lane * 16u;
            const unsigned src = L ^ (((L >> 8) & 15u) << 4);
            gload_lds16(gBt + src, bufs[tile] + Lb);
        }
    }
    asm volatile("s_waitcnt vmcnt(2)" ::: "memory");   // tile0 done, tile1 in flight
    __builtin_amdgcn_s_barrier();
    __builtin_amdgcn_sched_barrier(0);

    float p[4][4];     // row partials across ALL tiles
    #pragma unroll
    for (int m = 0; m < 4; ++m)
        #pragma unroll
        for (int r = 0; r < 4; ++r)
            p[m][r] = 0.f;

    for (int tt = 0; tt < NT; ++tt) {
        char* slot = bufs[tt & 1];

        // ---- ds_read this tile's B fragments + tables ----
        bf16x8 bF[4];
        #pragma unroll
        for (int kc = 0; kc < 4; ++kc) {
            const int row = wx * 16 + lr;
            const unsigned addr = (unsigned)(row * 256 + kc * 64 + kg * 16)
                                  ^ ((unsigned)lr << 4);
            bF[kc] = *(const bf16x8*)(slot + addr);
        }
        const float s2c = ldsS2[tt * TCOLS + wx * 16 + lr];

        // acc init = -(s1' + s2')
        f32x4 acc[4];
        #pragma unroll
        for (int m = 0; m < 4; ++m) {
            const float4 ns1v = *(const float4*)(ldsS1 + wy * 64 + m * 16 + kg * 4);
            acc[m] = (f32x4){ns1v.x - s2c, ns1v.y - s2c,
                             ns1v.z - s2c, ns1v.w - s2c};
        }

        // all my LDS reads landed -> cross-wave handshake for slot reuse
        asm volatile("s_waitcnt lgkmcnt(0)" ::: "memory");
        __builtin_amdgcn_sched_barrier(0);
        __builtin_amdgcn_s_barrier();
        __builtin_amdgcn_sched_barrier(0);

        // issue prefetch of tile tt+2 into the slot just released
        if (tt + 2 < NT) {
            const char* gBn = gB + (size_t)(tt + 2) * (TCOLS * 256u);
            #pragma unroll
            for (int it = 0; it < 2; ++it) {
                const unsigned Lb  = it * 8192u + wid * 1024u;
                const unsigned L   = Lb + lane * 16u;
                const unsigned src = L ^ (((L >> 8) & 15u) << 4);
                gload_lds16(gBn + src, slot + Lb);
            }
        }

        // MFMA: K=128 in 4 chunks (operands all in registers now)
        __builtin_amdgcn_s_setprio(1);
        #pragma unroll
        for (int kc = 0; kc < 4; ++kc)
            #pragma unroll
            for (int m = 0; m < 4; ++m)
                acc[m] = __builtin_amdgcn_mfma_f32_16x16x32_bf16(
                    aR[m * 4 + kc], bF[kc], acc[m], 0, 0, 0);
        __builtin_amdgcn_s_setprio(0);

        // ---- underflow-guarded epilogue ----
        // exp2f(x) == 0.0f exactly for x < -149 (below subnormal range).
        float mxa = fmaxf(fmaxf(acc[0][0], acc[0][1]), fmaxf(acc[0][2], acc[0][3]));
        float mxb = fmaxf(fmaxf(acc[1][0], acc[1][1]), fmaxf(acc[1][2], acc[1][3]));
        float mxc = fmaxf(fmaxf(acc[2][0], acc[2][1]), fmaxf(acc[2][2], acc[2][3]));
        float mxd = fmaxf(fmaxf(acc[3][0], acc[3][1]), fmaxf(acc[3][2], acc[3][3]));
        const float mx = fmaxf(fmaxf(mxa, mxb), fmaxf(mxc, mxd));
        if (__any(mx > -149.0f)) {
            #pragma unroll
            for (int m = 0; m < 4; ++m)
                #pragma unroll
                for (int r = 0; r < 4; ++r)
                    p[m][r] += __builtin_amdgcn_exp2f(acc[m][r]);
        }

        // counted end-of-tile drain: tile tt+1 ready; tt+2's loads in flight
        if (tt + 2 < NT) {
            asm volatile("s_waitcnt vmcnt(2)" ::: "memory");
            __builtin_amdgcn_s_barrier();
            __builtin_amdgcn_sched_barrier(0);
        } else if (tt + 1 < NT) {
            asm volatile("s_waitcnt vmcnt(0)" ::: "memory");
            __builtin_amdgcn_s_barrier();
            __builtin_amdgcn_sched_barrier(0);
        }
    }

    // ---- reduce partials over the 16 col-lanes; one store per (row, wx) ----
    const size_t plane = (size_t)(blockIdx.x * 4 + wx) * (size_t)Ntot;
    #pragma unroll
    for (int m = 0; m < 4; ++m) {
        #pragma unroll
        for (int r = 0; r < 4; ++r) {
            float v = p[m][r];
            v += __shfl_xor(v, 1, 64);
            v += __shfl_xor(v, 2, 64);
            v += __shfl_xor(v, 4, 64);
            v += __shfl_xor(v, 8, 64);
            if (lr == 0)
                partials[plane + brow + wy * 64 + m * 16 + kg * 4 + r] = v;
        }
    }
}

// Per-row finish: rep_i = (sum of planes)/N, loss term, att; block-reduce the
// three sums -> blocksums[3][64]. 64 blocks x 256 threads, one i per thread.
__global__ __launch_bounds__(256) void rowsum_kernel(
    const float* __restrict__ partials, const float* __restrict__ att,
    float* __restrict__ blocksums, int N)
{
    __shared__ float sm[3][4];
    const int i = blockIdx.x * 256 + threadIdx.x;
    const float inv = 1.0f / (float)N;
    float s = 0.f;
    #pragma unroll
    for (int pl = 0; pl < 4 * NCHUNK; ++pl)
        s += partials[(size_t)pl * N + i];
    const float rp = s * inv;
    const float at = att[i];
    float ls = log1pf(rp / (at + EPS));
    float sa = at;
    float sr = rp;
    #pragma unroll
    for (int m = 32; m; m >>= 1) {
        ls += __shfl_xor(ls, m, 64);
        sa += __shfl_xor(sa, m, 64);
        sr += __shfl_xor(sr, m, 64);
    }
    const int w = threadIdx.x >> 6, lane = threadIdx.x & 63;
    if (lane == 0) { sm[0][w] = ls; sm[1][w] = sa; sm[2][w] = sr; }
    __syncthreads();
    if (threadIdx.x < 3) {
        const float v = sm[threadIdx.x][0] + sm[threadIdx.x][1]
                      + sm[threadIdx.x][2] + sm[threadIdx.x][3];
        blocksums[threadIdx.x * 64 + blockIdx.x] = v;
    }
}

// Final: 3 waves, wave w reduces blocksums[w][0..63] -> out[w] / N.
__global__ __launch_bounds__(192) void final_kernel(
    const float* __restrict__ blocksums, float* __restrict__ out, int N)
{
    const int w = threadIdx.x >> 6;      // 0..2 output component
    const int lane = threadIdx.x & 63;
    float v = blocksums[w * 64 + lane];
    #pragma unroll
    for (int m = 32; m; m >>= 1) v += __shfl_xor(v, m, 64);
    if (lane == 0) out[w] = v / (float)N;
}

extern "C" void kernel_launch(void* const* d_in, const int* in_sizes, int n_in,
                              void* d_out, int out_size, void* d_ws, size_t ws_size,
                              hipStream_t stream)
{
    const float* X1 = (const float*)d_in[0];
    const float* X2 = (const float*)d_in[1];
    const int N = in_sizes[0] / D_DIM;   // 16384
    float* out = (float*)d_out;

    char* ws = (char*)d_ws;
    ushort* B1 = (ushort*)ws;                                  // N*128*2 B
    ushort* B2 = (ushort*)(ws + (size_t)N * D_DIM * 2);        // N*128*2 B
    float* sq1n = (float*)(ws + (size_t)N * D_DIM * 4);
    float* sq2 = sq1n + N;
    float* att = sq2 + N;
    float* partials = att + N;           // [4*NCHUNK][N] = 2 MB
    float* blocksums = partials + (size_t)4 * NCHUNK * N;   // 192 floats
    // total ws use ~= 10.4 MB

    prep_kernel<<<N / 4, 256, 0, stream>>>(X1, X2, B1, B2, sq1n, sq2, att);
    dim3 grid(NCHUNK, N / BM);
    cross_kernel<<<grid, 512, 0, stream>>>(B1, B2, sq1n, sq2, partials, N);
    rowsum_kernel<<<N / 256, 256, 0, stream>>>(partials, att, blocksums, N);
    final_kernel<<<1, 192, 0, stream>>>(blocksums, out, N);
}